// Round 9
// baseline (237.637 us; speedup 1.0000x reference)
//
#include <hip/hip_runtime.h>
#include <hip/hip_fp16.h>
#include <cstdint>
#include <cstddef>

#define D 128
typedef unsigned short u16;
typedef short bf16x8 __attribute__((ext_vector_type(8)));
typedef float f32x4 __attribute__((ext_vector_type(4)));

// bf16 pack/unpack (RTNE)
__device__ __forceinline__ u16 f2b(float f) {
    uint32_t u = __float_as_uint(f);
    return (u16)((u + 0x7FFFu + ((u >> 16) & 1u)) >> 16);
}
__device__ __forceinline__ float b2f(u16 b) {
    return __uint_as_float(((uint32_t)b) << 16);
}

// XOR swizzle on bf16 k-index within a [rows][128] LDS tile (16B groups)
#define SWZ(r, k) ((k) ^ (((r) & 7) << 3))

// ---------------- K0: fold weights -> bf16 Bcat ----------------
__global__ void k_prep(const float* __restrict__ Wq, const float* __restrict__ Wk,
                       const float* __restrict__ Wv, const float* __restrict__ Wg,
                       const float* __restrict__ bg, const float* __restrict__ Wl,
                       const float* __restrict__ bl,
                       u16* __restrict__ Bcatb, float* __restrict__ biasout)
{
    const int b = blockIdx.x;
    const int t = threadIdx.x; // 128
    if (b < 640) {
        const int strip = b >> 7, n = b & 127;
        float val;
        if (strip == 0) {
            val = Wq[t * D + n];
        } else if (strip == 1) {
            val = Wk[t * D + n];
        } else if (strip == 2) {
            float s = 0.f;
#pragma unroll 8
            for (int m = 0; m < D; ++m) s += Wv[t * D + m] * Wl[n * D + m];
            val = s;
        } else if (strip == 3) {
            val = Wl[n * D + t];
        } else {
            float s = 0.f;
#pragma unroll 8
            for (int m = 0; m < D; ++m) s += Wl[n * D + m] * Wg[m * D + t];
            val = 0.6f * s;
        }
        Bcatb[(size_t)b * D + t] = f2b(val);
    } else {
        float s = 0.f;
#pragma unroll 8
        for (int m = 0; m < D; ++m) s += bg[m] * Wl[t * D + m];
        biasout[t] = bl[t] + 0.6f * s;
    }
}

// zero cnt
__global__ void k_init(int* __restrict__ cnt, int M)
{
    const int i = blockIdx.x * 256 + threadIdx.x;
    if (i < M) cnt[i] = 0;
}

// histogram + record within-segment position (kills the fill atomic)
__global__ void k_hist(const int* __restrict__ dst, int* __restrict__ cnt,
                       int* __restrict__ epos, int E)
{
    const int e = blockIdx.x * 256 + threadIdx.x;
    if (e < E) epos[e] = atomicAdd(&cnt[dst[e]], 1);
}

// ---------------- hierarchical exclusive scan (+ dinv fused) ----------------
__global__ __launch_bounds__(1024) void k_scan1(const int* __restrict__ cnt,
                                                int* __restrict__ offs,
                                                int* __restrict__ bsum,
                                                float* __restrict__ dinv, int M)
{
    __shared__ int wsum[16];
    const int t = threadIdx.x, lane = t & 63, w = t >> 6;
    const int i = blockIdx.x * 1024 + t;
    const int v = (i < M) ? cnt[i] : 0;
    if (i < M) dinv[i] = rsqrtf((float)(v + 1)); // +1 self loop
    int s = v;
    for (int off = 1; off < 64; off <<= 1) {
        int n = __shfl_up(s, off);
        if (lane >= off) s += n;
    }
    if (lane == 63) wsum[w] = s;
    __syncthreads();
    if (w == 0) {
        int ss = (lane < 16) ? wsum[lane] : 0;
        for (int off = 1; off < 16; off <<= 1) {
            int n = __shfl_up(ss, off);
            if (lane >= off) ss += n;
        }
        if (lane < 16) wsum[lane] = ss;
    }
    __syncthreads();
    const int woff = (w == 0) ? 0 : wsum[w - 1];
    if (i < M) offs[i] = woff + s - v;
    if (t == 1023) bsum[blockIdx.x] = wsum[15];
}

__global__ void k_scanB(int* __restrict__ bsum, int nb) // 1 block, 64 threads
{
    const int t = threadIdx.x;
    int v = (t < nb) ? bsum[t] : 0;
    int s = v;
    for (int off = 1; off < 64; off <<= 1) {
        int n = __shfl_up(s, off);
        if (t >= off) s += n;
    }
    if (t < nb) bsum[t] = s - v; // exclusive
}

__global__ void k_scan2(const int* __restrict__ bsum, int* __restrict__ offs, int M)
{
    const int i = blockIdx.x * 256 + threadIdx.x;
    if (i < M) offs[i] += bsum[i >> 10];
}

// fill CSR, atomic-free: pos = offs[d] + epos[e]; payload = src(16b) | fp16(w)<<16.
__global__ void k_fill(const int* __restrict__ src, const int* __restrict__ dst,
                       const int* __restrict__ epos,
                       const float* __restrict__ dinv,
                       const int* __restrict__ offs,
                       uint32_t* __restrict__ cpk, int E)
{
    const int e = blockIdx.x * 256 + threadIdx.x;
    if (e < E) {
        const int s = src[e], d = dst[e];
        const int pos = offs[d] + epos[e];
        const float w = dinv[s] * dinv[d];
        const u16 hb = __half_as_ushort(__float2half(w));
        cpk[pos] = (uint32_t)(u16)s | ((uint32_t)hb << 16);
    }
}

// ---------------- x -> bf16 (one pass; gemm then reads bf16 10x) ----------------
__global__ void k_cvt(const float* __restrict__ x, u16* __restrict__ xb, size_t NQ)
{
    const size_t i = ((size_t)blockIdx.x * 256 + threadIdx.x) * 8;
    if (i >= NQ) return;
    const float4 a = *(const float4*)(x + i);
    const float4 b = *(const float4*)(x + i + 4);
    u16 r[8] = {f2b(a.x), f2b(a.y), f2b(a.z), f2b(a.w),
                f2b(b.x), f2b(b.y), f2b(b.z), f2b(b.w)};
    *(uint4*)(xb + i) = *(const uint4*)r;
}

// ---------------- K1: col-parallel MFMA GEMM + fused stats ----------------
// grid (10, NBG): blockIdx.x = B-chunk (fastest -> row-strip locality in L2/L3),
// blockIdx.y = 64-row strip. Chunks 0-1 = q (sumsq), 2-3 = k (sumsq + colsum).
__global__ __launch_bounds__(256) void k_gemm5(const u16* __restrict__ xb,
                                               const u16* __restrict__ Bcatb,
                                               u16* __restrict__ outbase,
                                               float* __restrict__ psq,
                                               float* __restrict__ psk,
                                               float* __restrict__ pks,
                                               int M, size_t NQ)
{
    __shared__ u16 As[64 * D];
    __shared__ u16 Bs[64 * D];
    __shared__ float lks[D];
    __shared__ float red[4];
    const int t = threadIdx.x;
    const int chunk = blockIdx.x;
    const int row0 = blockIdx.y * 64;

    if (t < D) lks[t] = 0.f;

#pragma unroll
    for (int p = 0; p < 4; ++p) {
        const int flat = t + 256 * p; // 1024 chunks of 8 bf16
        const int r = flat >> 4, kg = flat & 15;
        int gr = row0 + r; if (gr > M - 1) gr = M - 1;
        const uint4 v = *(const uint4*)(xb + (size_t)gr * D + kg * 8);
        *(uint4*)(As + r * D + SWZ(r, kg * 8)) = v;
    }
#pragma unroll
    for (int p = 0; p < 4; ++p) {
        const int flat = t + 256 * p;
        const int r = flat >> 4, kg = flat & 15;
        const uint4 v = *(const uint4*)(Bcatb + (size_t)(chunk * 64 + r) * D + kg * 8);
        *(uint4*)(Bs + r * D + SWZ(r, kg * 8)) = v;
    }
    __syncthreads();

    const int lane = t & 63, w = t >> 6;
    const int wr = (w >> 1) * 32, wc = (w & 1) * 32;
    const int fr = lane & 15, kg2 = lane >> 4;

    f32x4 acc[2][2] = {};
#pragma unroll
    for (int ks = 0; ks < 4; ++ks) {
        const int kb = ks * 32 + kg2 * 8;
        bf16x8 a[2], b[2];
#pragma unroll
        for (int i = 0; i < 2; ++i) {
            const int r = wr + 16 * i + fr;
            a[i] = *(const bf16x8*)(As + r * D + SWZ(r, kb));
        }
#pragma unroll
        for (int j = 0; j < 2; ++j) {
            const int r = wc + 16 * j + fr;
            b[j] = *(const bf16x8*)(Bs + r * D + SWZ(r, kb));
        }
#pragma unroll
        for (int i = 0; i < 2; ++i)
#pragma unroll
            for (int j = 0; j < 2; ++j)
                acc[i][j] = __builtin_amdgcn_mfma_f32_16x16x32_bf16(a[i], b[j], acc[i][j], 0, 0, 0);
    }

    const int mat = chunk >> 1, col0 = (chunk & 1) * 64;
    u16* outp = outbase + (size_t)mat * NQ;
    float sacc = 0.f; // sumsq(q) for chunks 0-1, sumsq(k) for 2-3
#pragma unroll
    for (int i = 0; i < 2; ++i) {
#pragma unroll
        for (int reg = 0; reg < 4; ++reg) {
            const int r = row0 + wr + 16 * i + kg2 * 4 + reg; // C/D: row=(lane>>4)*4+reg
            if (r < M) {
#pragma unroll
                for (int j = 0; j < 2; ++j) {
                    const int col = col0 + wc + 16 * j + fr;  // C/D: col=lane&15
                    const u16 hv = f2b(acc[i][j][reg]);
                    outp[(size_t)r * D + col] = hv;
                    if (chunk < 4) {
                        const float v = b2f(hv);
                        sacc += v * v;
                        if (chunk >= 2) atomicAdd(&lks[col], v);
                    }
                }
            }
        }
    }

    if (chunk < 4) {
        for (int off = 32; off > 0; off >>= 1) sacc += __shfl_down(sacc, off);
        __syncthreads(); // lks atomics complete
        if ((t & 63) == 0) red[w] = sacc;
        __syncthreads();
        const int pb = blockIdx.y * 2 + (chunk & 1);
        if (t == 0) {
            const float s = red[0] + red[1] + red[2] + red[3];
            if (chunk < 2) psq[pb] = s; else psk[pb] = s;
        }
        if (chunk >= 2 && t < D) pks[(size_t)pb * D + t] = lks[t];
    }
}

// ---------------- K2: MFMA split-K C = k^T @ vW ----------------
__global__ __launch_bounds__(256) void k_ktv(const u16* __restrict__ kb,
                                             const u16* __restrict__ vWb,
                                             float* __restrict__ part, int M)
{
    __shared__ u16 kT[D * 64];
    __shared__ u16 vT[D * 64];
    const int t = threadIdx.x;
    const int P = (int)gridDim.x;
    const int chunk = (M + P - 1) / P;
    const int rbeg = blockIdx.x * chunk;
    const int rend = min(rbeg + chunk, M);

    const int lane = t & 63, w = t >> 6;
    const int fr = lane & 15, kg = lane >> 4;

    f32x4 acc[2][8] = {};

    for (int r0 = rbeg; r0 < rend; r0 += 64) {
#pragma unroll
        for (int p = 0; p < 4; ++p) {
            const int flat = t + 256 * p;
            const int rr = flat & 63, cg = flat >> 6;
            const int gr = r0 + rr;
            uint4 kv = make_uint4(0, 0, 0, 0), vv = make_uint4(0, 0, 0, 0);
            if (gr < rend) {
                kv = *(const uint4*)(kb + (size_t)gr * D + cg * 8);
                vv = *(const uint4*)(vWb + (size_t)gr * D + cg * 8);
            }
            const u16* kp = (const u16*)&kv;
            const u16* vp = (const u16*)&vv;
#pragma unroll
            for (int jj = 0; jj < 8; ++jj) {
                const int c = cg * 8 + jj;
                const int ri = rr ^ ((c & 7) << 3);
                kT[c * 64 + ri] = kp[jj];
                vT[c * 64 + ri] = vp[jj];
            }
        }
        __syncthreads();
#pragma unroll
        for (int ks = 0; ks < 2; ++ks) {
            const int rb = ks * 32 + kg * 8;
            bf16x8 a[2], b[8];
#pragma unroll
            for (int i = 0; i < 2; ++i) {
                const int m = w * 32 + 16 * i + fr;
                a[i] = *(const bf16x8*)(kT + m * 64 + (rb ^ ((m & 7) << 3)));
            }
#pragma unroll
            for (int j = 0; j < 8; ++j) {
                const int n = 16 * j + fr;
                b[j] = *(const bf16x8*)(vT + n * 64 + (rb ^ ((n & 7) << 3)));
            }
#pragma unroll
            for (int i = 0; i < 2; ++i)
#pragma unroll
                for (int j = 0; j < 8; ++j)
                    acc[i][j] = __builtin_amdgcn_mfma_f32_16x16x32_bf16(a[i], b[j], acc[i][j], 0, 0, 0);
        }
        __syncthreads();
    }
    float* pp = part + (size_t)blockIdx.x * (D * D);
#pragma unroll
    for (int i = 0; i < 2; ++i)
#pragma unroll
        for (int reg = 0; reg < 4; ++reg) {
            const int m = w * 32 + 16 * i + kg * 4 + reg;
#pragma unroll
            for (int j = 0; j < 8; ++j)
                pp[(size_t)m * D + 16 * j + fr] = acc[i][j][reg];
        }
}

// unrolled split-K reduce: 8 independent loads in flight per thread
__global__ void k_redC(const float* __restrict__ part, float* __restrict__ Craw, int P)
{
    const int e = blockIdx.x * 256 + threadIdx.x; // 16384
    float s0 = 0.f, s1 = 0.f, s2 = 0.f, s3 = 0.f,
          s4 = 0.f, s5 = 0.f, s6 = 0.f, s7 = 0.f;
    int p = 0;
    for (; p + 8 <= P; p += 8) {
        s0 += part[(size_t)(p + 0) * (D * D) + e];
        s1 += part[(size_t)(p + 1) * (D * D) + e];
        s2 += part[(size_t)(p + 2) * (D * D) + e];
        s3 += part[(size_t)(p + 3) * (D * D) + e];
        s4 += part[(size_t)(p + 4) * (D * D) + e];
        s5 += part[(size_t)(p + 5) * (D * D) + e];
        s6 += part[(size_t)(p + 6) * (D * D) + e];
        s7 += part[(size_t)(p + 7) * (D * D) + e];
    }
    for (; p < P; ++p) s0 += part[(size_t)p * (D * D) + e];
    Craw[e] = ((s0 + s1) + (s2 + s3)) + ((s4 + s5) + (s6 + s7));
}

// ---------------- merged: reduce stats partials -> kq, inv; emit C3b ----------------
// 1 block x 1024 threads; NBLK arbitrary (loops handle > 1024).
__global__ __launch_bounds__(1024) void k_scalc3t(const float* __restrict__ psq,
                                                  const float* __restrict__ psk,
                                                  const float* __restrict__ pks,
                                                  const float* __restrict__ Craw,
                                                  float* __restrict__ kq,
                                                  u16* __restrict__ C3b, int NBLK)
{
    __shared__ float lpart[8][D];
    __shared__ float wredA[16];
    __shared__ float wredB[16];
    __shared__ float invS;
    const int t = threadIdx.x;
    const int col = t & 127, grp = t >> 7; // 8 groups x 128 cols
    float s = 0.f;
#pragma unroll 8
    for (int bq = grp; bq < NBLK; bq += 8) s += pks[(size_t)bq * D + col];
    lpart[grp][col] = s;
    // sumsq reduce (any NBLK)
    const int w = t >> 6, lane = t & 63;
    float a = 0.f, b = 0.f;
    for (int i = t; i < NBLK; i += 1024) { a += psq[i]; b += psk[i]; }
    for (int off = 32; off > 0; off >>= 1) {
        a += __shfl_down(a, off);
        b += __shfl_down(b, off);
    }
    if (lane == 0) { wredA[w] = a; wredB[w] = b; }
    __syncthreads();
    if (t == 0) {
        float sq = 0.f, sk = 0.f;
#pragma unroll
        for (int i = 0; i < 16; ++i) { sq += wredA[i]; sk += wredB[i]; }
        invS = 1.0f / (sqrtf(sq) * sqrtf(sk) * 128.0f);
    }
    float ks = 0.f;
    if (t < D) {
#pragma unroll
        for (int g = 0; g < 8; ++g) ks += lpart[g][t];
    }
    __syncthreads();
    const float inv = invS;
    if (t < D) kq[t] = ks * inv;
#pragma unroll
    for (int i = 0; i < 16; ++i) {
        const int e = t + 1024 * i;
        C3b[e] = f2b(Craw[(size_t)(e & 127) * D + (e >> 7)] * inv);
    }
}

// ---------------- K4: MFMA qb @ C3b^T + fused qk/scale + epilogue ----------------
__global__ __launch_bounds__(256) void k_final(const u16* __restrict__ qb,
                                               const u16* __restrict__ C3b,
                                               const u16* __restrict__ vWb,
                                               const u16* __restrict__ xWb,
                                               const u16* __restrict__ ub,
                                               const int* __restrict__ cnt,
                                               const float* __restrict__ kq,
                                               const float* __restrict__ biasout,
                                               float* __restrict__ out, int M)
{
    __shared__ u16 As[64 * D];
    __shared__ u16 Bs[D * D];
    __shared__ float scaleS[64];
    const int t = threadIdx.x;
    const int row0 = blockIdx.x * 64;

#pragma unroll
    for (int p = 0; p < 4; ++p) {
        const int flat = t + 256 * p;
        const int r = flat >> 4, kg2 = flat & 15;
        int gr = row0 + r; if (gr > M - 1) gr = M - 1;
        const uint4 v = *(const uint4*)(qb + (size_t)gr * D + kg2 * 8);
        *(uint4*)(As + r * D + SWZ(r, kg2 * 8)) = v;
    }
#pragma unroll
    for (int p = 0; p < 8; ++p) {
        const int flat = t + 256 * p;
        const int r = flat >> 4, kg2 = flat & 15;
        const uint4 v = *(const uint4*)(C3b + (size_t)r * D + kg2 * 8);
        *(uint4*)(Bs + r * D + SWZ(r, kg2 * 8)) = v;
    }
    __syncthreads();

    {
        const int rr = t >> 2, qq = t & 3;
        float s = 0.f;
#pragma unroll
        for (int i = 0; i < 4; ++i) {
            const int kk = qq * 32 + i * 8;
            const bf16x8 a = *(const bf16x8*)(As + rr * D + SWZ(rr, kk));
            const u16* ap = (const u16*)&a;
#pragma unroll
            for (int jj = 0; jj < 8; ++jj) s += b2f(ap[jj]) * kq[kk + jj];
        }
        s += __shfl_xor(s, 1);
        s += __shfl_xor(s, 2);
        if (qq == 0) scaleS[rr] = 0.16f / (1.0f + s);
    }

    const int lane = t & 63, w = t >> 6;
    const int fr = lane & 15, kg = lane >> 4;

    f32x4 acc[8] = {};
#pragma unroll
    for (int ks = 0; ks < 4; ++ks) {
        const int kb2 = ks * 32 + kg * 8;
        const int r = w * 16 + fr;
        const bf16x8 a = *(const bf16x8*)(As + r * D + SWZ(r, kb2));
#pragma unroll
        for (int j = 0; j < 8; ++j) {
            const int n = 16 * j + fr;
            const bf16x8 b = *(const bf16x8*)(Bs + n * D + SWZ(n, kb2));
            acc[j] = __builtin_amdgcn_mfma_f32_16x16x32_bf16(a, b, acc[j], 0, 0, 0);
        }
    }
    __syncthreads(); // scaleS ready

#pragma unroll
    for (int reg = 0; reg < 4; ++reg) {
        const int rr = w * 16 + kg * 4 + reg;
        const int r = row0 + rr;
        if (r < M) {
            const float rc = scaleS[rr];
            const float sc = 1.0f / (float)(cnt[r] + 1);
#pragma unroll
            for (int j = 0; j < 8; ++j) {
                const int c = 16 * j + fr;
                const size_t idx = (size_t)r * D + c;
                out[idx] = rc * (b2f(vWb[idx]) + acc[j][reg]) + 0.24f * b2f(xWb[idx])
                         + biasout[c] + sc * b2f(ub[idx]);
            }
        }
    }
}

// ---------------- K5: wave-cooperative CSR gather (packed payload) ----------------
__global__ __launch_bounds__(256) void k_gather(const int* __restrict__ offs,
                                                const int* __restrict__ cnt,
                                                const uint32_t* __restrict__ cpk,
                                                const u16* __restrict__ ub,
                                                float* __restrict__ out, int M)
{
    const int t = threadIdx.x;
    const int w = t >> 6, lane = t & 63;
    const int d = blockIdx.x * 4 + w;
    if (d >= M) return;
    const int g = lane >> 4, sub = lane & 15;
    const int beg = offs[d];
    const int n = cnt[d];
    if (n == 0) return;
    const int end = beg + n;
    float acc[8] = {};
    for (int j0 = beg; j0 < end; j0 += 8) {
        const int j1 = j0 + g, j2 = j0 + 4 + g;
        int s1 = 0, s2 = 0;
        float w1 = 0.f, w2 = 0.f;
        if (j1 < end) {
            const uint32_t p = cpk[j1];
            s1 = (int)(p & 0xFFFFu);
            w1 = __half2float(__ushort_as_half((u16)(p >> 16)));
        }
        if (j2 < end) {
            const uint32_t p = cpk[j2];
            s2 = (int)(p & 0xFFFFu);
            w2 = __half2float(__ushort_as_half((u16)(p >> 16)));
        }
        const uint4 r1 = *(const uint4*)(ub + (size_t)s1 * D + sub * 8);
        const uint4 r2 = *(const uint4*)(ub + (size_t)s2 * D + sub * 8);
        const u16* p1 = (const u16*)&r1;
        const u16* p2 = (const u16*)&r2;
#pragma unroll
        for (int i = 0; i < 8; ++i) acc[i] += w1 * b2f(p1[i]) + w2 * b2f(p2[i]);
    }
#pragma unroll
    for (int i = 0; i < 8; ++i) {
        acc[i] += __shfl_xor(acc[i], 16);
        acc[i] += __shfl_xor(acc[i], 32);
    }
    if (g == 0) {
        float* o = out + (size_t)d * D + sub * 8;
        float4 o0 = *(float4*)o, o1 = *(float4*)(o + 4);
        o0.x += acc[0]; o0.y += acc[1]; o0.z += acc[2]; o0.w += acc[3];
        o1.x += acc[4]; o1.y += acc[5]; o1.z += acc[6]; o1.w += acc[7];
        *(float4*)o = o0; *(float4*)(o + 4) = o1;
    }
}

extern "C" void kernel_launch(void* const* d_in, const int* in_sizes, int n_in,
                              void* d_out, int out_size, void* d_ws, size_t ws_size,
                              hipStream_t stream)
{
    const float* x  = (const float*)d_in[0];
    const int*   ei = (const int*)d_in[1];
    const float* Wq = (const float*)d_in[2];
    const float* Wk = (const float*)d_in[3];
    const float* Wv = (const float*)d_in[4];
    const float* Wg = (const float*)d_in[5];
    const float* bg = (const float*)d_in[6];
    const float* Wl = (const float*)d_in[7];
    const float* bl = (const float*)d_in[8];

    const int M = in_sizes[0] / D;
    const int E = in_sizes[1] / 2;
    const size_t NQ = (size_t)M * D;
    const int P = 192;
    const int NBG = (M + 63) / 64;      // row strips
    const int NPART = 2 * NBG;          // stats partials
    const int NB = (M + 1023) / 1024;

    char* base = (char*)d_ws;
    auto alloc = [&](size_t bytes) -> char* {
        char* p = base; base += (bytes + 63) & ~(size_t)63; return p;
    };
    float* part    = (float*)alloc((size_t)P * D * D * 4);
    float* Craw    = (float*)alloc(D * D * 4);
    float* dinv    = (float*)alloc((size_t)M * 4);
    float* psq     = (float*)alloc((size_t)NPART * 4);
    float* psk     = (float*)alloc((size_t)NPART * 4);
    float* pks     = (float*)alloc((size_t)NPART * D * 4);
    float* kq      = (float*)alloc(D * 4);
    float* biasout = (float*)alloc(D * 4);
    int*   cnt     = (int*)alloc((size_t)M * 4);
    int*   offs    = (int*)alloc((size_t)M * 4);
    int*   bsum    = (int*)alloc(64 * 4);
    int*   epos    = (int*)alloc((size_t)E * 4);
    uint32_t* cpk  = (uint32_t*)alloc((size_t)E * 4);
    u16*   Bcatb   = (u16*)alloc((size_t)640 * D * 2);
    u16*   C3b     = (u16*)alloc(D * D * 2);
    u16*   xb      = (u16*)alloc(NQ * 2);
    u16*   qb      = (u16*)alloc(NQ * 2); // qb..ub contiguous
    u16*   kb      = (u16*)alloc(NQ * 2);
    u16*   vWb     = (u16*)alloc(NQ * 2);
    u16*   xWb     = (u16*)alloc(NQ * 2);
    u16*   ub      = (u16*)alloc(NQ * 2);
    (void)kb; (void)vWb; (void)xWb;

    float* out = (float*)d_out;

    // weights + CSR build
    k_prep<<<dim3(641), dim3(128), 0, stream>>>(Wq, Wk, Wv, Wg, bg, Wl, bl, Bcatb, biasout);
    k_init<<<(M + 255) / 256, 256, 0, stream>>>(cnt, M);
    k_hist<<<(E + 255) / 256, 256, 0, stream>>>(ei + E, cnt, epos, E);
    k_scan1<<<NB, 1024, 0, stream>>>(cnt, offs, bsum, dinv, M);
    k_scanB<<<1, 64, 0, stream>>>(bsum, NB);
    k_scan2<<<(M + 255) / 256, 256, 0, stream>>>(bsum, offs, M);
    k_fill<<<(E + 255) / 256, 256, 0, stream>>>(ei, ei + E, epos, dinv, offs, cpk, E);

    // dense chain (bf16 MFMA)
    k_cvt<<<(int)((NQ / 8 + 255) / 256), 256, 0, stream>>>(x, xb, NQ);
    k_gemm5<<<dim3(10, NBG), 256, 0, stream>>>(xb, Bcatb, qb, psq, psk, pks, M, NQ);
    k_ktv<<<P, 256, 0, stream>>>(kb, vWb, part, M);
    k_redC<<<64, 256, 0, stream>>>(part, Craw, P);
    k_scalc3t<<<1, 1024, 0, stream>>>(psq, psk, pks, Craw, kq, C3b, NPART);

    k_final<<<(M + 63) / 64, 256, 0, stream>>>(qb, C3b, vWb, xWb, ub, cnt, kq, biasout, out, M);
    k_gather<<<(M + 3) / 4, 256, 0, stream>>>(offs, cnt, cpk, ub, out, M);
}

// Round 10
// 194.031 us; speedup vs baseline: 1.2247x; 1.2247x over previous
//
#include <hip/hip_runtime.h>
#include <hip/hip_fp16.h>
#include <cstdint>
#include <cstddef>

#define D 128
typedef unsigned short u16;
typedef short bf16x8 __attribute__((ext_vector_type(8)));
typedef float f32x4 __attribute__((ext_vector_type(4)));

// bf16 pack/unpack (RTNE)
__device__ __forceinline__ u16 f2b(float f) {
    uint32_t u = __float_as_uint(f);
    return (u16)((u + 0x7FFFu + ((u >> 16) & 1u)) >> 16);
}
__device__ __forceinline__ float b2f(u16 b) {
    return __uint_as_float(((uint32_t)b) << 16);
}

// XOR swizzle on bf16 k-index within a [rows][128] LDS tile (16B groups)
#define SWZ(r, k) ((k) ^ (((r) & 7) << 3))

// ---------------- K0: fold weights -> bf16 Bcat ----------------
__global__ void k_prep(const float* __restrict__ Wq, const float* __restrict__ Wk,
                       const float* __restrict__ Wv, const float* __restrict__ Wg,
                       const float* __restrict__ bg, const float* __restrict__ Wl,
                       const float* __restrict__ bl,
                       u16* __restrict__ Bcatb, float* __restrict__ biasout)
{
    const int b = blockIdx.x;
    const int t = threadIdx.x; // 128
    if (b < 640) {
        const int strip = b >> 7, n = b & 127;
        float val;
        if (strip == 0) {
            val = Wq[t * D + n];
        } else if (strip == 1) {
            val = Wk[t * D + n];
        } else if (strip == 2) {
            float s = 0.f;
#pragma unroll 8
            for (int m = 0; m < D; ++m) s += Wv[t * D + m] * Wl[n * D + m];
            val = s;
        } else if (strip == 3) {
            val = Wl[n * D + t];
        } else {
            float s = 0.f;
#pragma unroll 8
            for (int m = 0; m < D; ++m) s += Wl[n * D + m] * Wg[m * D + t];
            val = 0.6f * s;
        }
        Bcatb[(size_t)b * D + t] = f2b(val);
    } else {
        float s = 0.f;
#pragma unroll 8
        for (int m = 0; m < D; ++m) s += bg[m] * Wl[t * D + m];
        biasout[t] = bl[t] + 0.6f * s;
    }
}

// zero cnt
__global__ void k_init(int* __restrict__ cnt, int M)
{
    const int i = blockIdx.x * 256 + threadIdx.x;
    if (i < M) cnt[i] = 0;
}

// histogram + record within-segment position (kills the fill atomic)
__global__ void k_hist(const int* __restrict__ dst, int* __restrict__ cnt,
                       int* __restrict__ epos, int E)
{
    const int e = blockIdx.x * 256 + threadIdx.x;
    if (e < E) epos[e] = atomicAdd(&cnt[dst[e]], 1);
}

// ---------------- hierarchical exclusive scan (+ dinv fused) ----------------
__global__ __launch_bounds__(1024) void k_scan1(const int* __restrict__ cnt,
                                                int* __restrict__ offs,
                                                int* __restrict__ bsum,
                                                float* __restrict__ dinv, int M)
{
    __shared__ int wsum[16];
    const int t = threadIdx.x, lane = t & 63, w = t >> 6;
    const int i = blockIdx.x * 1024 + t;
    const int v = (i < M) ? cnt[i] : 0;
    if (i < M) dinv[i] = rsqrtf((float)(v + 1)); // +1 self loop
    int s = v;
    for (int off = 1; off < 64; off <<= 1) {
        int n = __shfl_up(s, off);
        if (lane >= off) s += n;
    }
    if (lane == 63) wsum[w] = s;
    __syncthreads();
    if (w == 0) {
        int ss = (lane < 16) ? wsum[lane] : 0;
        for (int off = 1; off < 16; off <<= 1) {
            int n = __shfl_up(ss, off);
            if (lane >= off) ss += n;
        }
        if (lane < 16) wsum[lane] = ss;
    }
    __syncthreads();
    const int woff = (w == 0) ? 0 : wsum[w - 1];
    if (i < M) offs[i] = woff + s - v;
    if (t == 1023) bsum[blockIdx.x] = wsum[15];
}

__global__ void k_scanB(int* __restrict__ bsum, int nb) // 1 block, 64 threads
{
    const int t = threadIdx.x;
    int v = (t < nb) ? bsum[t] : 0;
    int s = v;
    for (int off = 1; off < 64; off <<= 1) {
        int n = __shfl_up(s, off);
        if (t >= off) s += n;
    }
    if (t < nb) bsum[t] = s - v; // exclusive
}

__global__ void k_scan2(const int* __restrict__ bsum, int* __restrict__ offs, int M)
{
    const int i = blockIdx.x * 256 + threadIdx.x;
    if (i < M) offs[i] += bsum[i >> 10];
}

// fill CSR, atomic-free: pos = offs[d] + epos[e]; payload = src(16b) | fp16(w)<<16.
__global__ void k_fill(const int* __restrict__ src, const int* __restrict__ dst,
                       const int* __restrict__ epos,
                       const float* __restrict__ dinv,
                       const int* __restrict__ offs,
                       uint32_t* __restrict__ cpk, int E)
{
    const int e = blockIdx.x * 256 + threadIdx.x;
    if (e < E) {
        const int s = src[e], d = dst[e];
        const int pos = offs[d] + epos[e];
        const float w = dinv[s] * dinv[d];
        const u16 hb = __half_as_ushort(__float2half(w));
        cpk[pos] = (uint32_t)(u16)s | ((uint32_t)hb << 16);
    }
}

// ---------------- K1: col-parallel MFMA GEMM, 2 chunks/block + fused stats ----------------
// grid (NBG, 5): blockIdx.x = 64-row strip (FASTEST -> round-7-proven dispatch order),
// blockIdx.y = pair p -> chunks (2p, 2p+1) = full output matrix p (cols 0-63, 64-127).
// A staged once per block (fp32 -> bf16); B restaged between chunks.
// pair 0 = q: sumsq partials. pair 1 = k: sumsq + colsum partials.
__global__ __launch_bounds__(256) void k_gemm5(const float* __restrict__ x,
                                               const u16* __restrict__ Bcatb,
                                               u16* __restrict__ outbase,
                                               float* __restrict__ psq,
                                               float* __restrict__ psk,
                                               float* __restrict__ pks,
                                               int M, size_t NQ)
{
    __shared__ u16 As[64 * D];
    __shared__ u16 Bs[64 * D];
    __shared__ float lks[D];
    __shared__ float red[4];
    const int t = threadIdx.x;
    const int row0 = blockIdx.x * 64;
    const int pair = blockIdx.y;

    if (t < D) lks[t] = 0.f;

    // stage A (fp32 -> bf16)
#pragma unroll
    for (int p = 0; p < 4; ++p) {
        const int flat = t + 256 * p; // 1024 chunks of 8
        const int r = flat >> 4, kg = flat & 15;
        int gr = row0 + r; if (gr > M - 1) gr = M - 1;
        const float4 f0 = *(const float4*)(x + (size_t)gr * D + kg * 8);
        const float4 f1 = *(const float4*)(x + (size_t)gr * D + kg * 8 + 4);
        u16 rr[8] = {f2b(f0.x), f2b(f0.y), f2b(f0.z), f2b(f0.w),
                     f2b(f1.x), f2b(f1.y), f2b(f1.z), f2b(f1.w)};
        *(uint4*)(As + r * D + SWZ(r, kg * 8)) = *(const uint4*)rr;
    }
    // stage B chunk 2*pair
#pragma unroll
    for (int p = 0; p < 4; ++p) {
        const int flat = t + 256 * p;
        const int r = flat >> 4, kg = flat & 15;
        const uint4 v = *(const uint4*)(Bcatb + (size_t)(2 * pair * 64 + r) * D + kg * 8);
        *(uint4*)(Bs + r * D + SWZ(r, kg * 8)) = v;
    }
    __syncthreads();

    const int lane = t & 63, w = t >> 6;
    const int wr = (w >> 1) * 32, wc = (w & 1) * 32;
    const int fr = lane & 15, kg2 = lane >> 4;

    u16* outp = outbase + (size_t)pair * NQ;
    float sacc = 0.f;
    float kc[4] = {0.f, 0.f, 0.f, 0.f};

#pragma unroll
    for (int h = 0; h < 2; ++h) {
        f32x4 acc[2][2] = {};
#pragma unroll
        for (int ks = 0; ks < 4; ++ks) {
            const int kb = ks * 32 + kg2 * 8;
            bf16x8 a[2], b[2];
#pragma unroll
            for (int i = 0; i < 2; ++i) {
                const int r = wr + 16 * i + fr;
                a[i] = *(const bf16x8*)(As + r * D + SWZ(r, kb));
            }
#pragma unroll
            for (int j = 0; j < 2; ++j) {
                const int r = wc + 16 * j + fr;
                b[j] = *(const bf16x8*)(Bs + r * D + SWZ(r, kb));
            }
#pragma unroll
            for (int i = 0; i < 2; ++i)
#pragma unroll
                for (int j = 0; j < 2; ++j)
                    acc[i][j] = __builtin_amdgcn_mfma_f32_16x16x32_bf16(a[i], b[j], acc[i][j], 0, 0, 0);
        }
        __syncthreads(); // all waves done reading Bs
        if (h == 0) {
            // restage Bs with chunk 2*pair+1 (overlaps with epilogue stores below)
#pragma unroll
            for (int p = 0; p < 4; ++p) {
                const int flat = t + 256 * p;
                const int r = flat >> 4, kg = flat & 15;
                const uint4 v = *(const uint4*)(Bcatb + (size_t)((2 * pair + 1) * 64 + r) * D + kg * 8);
                *(uint4*)(Bs + r * D + SWZ(r, kg * 8)) = v;
            }
        }

        // epilogue: store this chunk (cols h*64..h*64+63) + stats in registers
        const int col0 = h * 64;
#pragma unroll
        for (int i = 0; i < 2; ++i) {
#pragma unroll
            for (int reg = 0; reg < 4; ++reg) {
                const int r = row0 + wr + 16 * i + kg2 * 4 + reg; // C/D: row=(lane>>4)*4+reg
                if (r < M) {
#pragma unroll
                    for (int j = 0; j < 2; ++j) {
                        const int col = col0 + wc + 16 * j + fr;  // C/D: col=lane&15
                        const u16 hv = f2b(acc[i][j][reg]);
                        outp[(size_t)r * D + col] = hv;
                        if (pair < 2) {
                            const float v = b2f(hv);
                            sacc += v * v;
                            if (pair == 1) kc[h * 2 + j] += v;
                        }
                    }
                }
            }
        }
        if (h == 0) __syncthreads(); // Bs restage visible
    }

    if (pair < 2) {
        if (pair == 1) {
#pragma unroll
            for (int h = 0; h < 2; ++h)
#pragma unroll
                for (int j = 0; j < 2; ++j)
                    atomicAdd(&lks[h * 64 + wc + 16 * j + fr], kc[h * 2 + j]);
        }
        for (int off = 32; off > 0; off >>= 1) sacc += __shfl_down(sacc, off);
        if ((t & 63) == 0) red[w] = sacc;
        __syncthreads(); // red + lks atomics complete
        if (t == 0) {
            const float s = red[0] + red[1] + red[2] + red[3];
            if (pair == 0) psq[blockIdx.x] = s; else psk[blockIdx.x] = s;
        }
        if (pair == 1 && t < D) pks[(size_t)blockIdx.x * D + t] = lks[t];
    }
}

// ---------------- K2: MFMA split-K C = k^T @ vW ----------------
__global__ __launch_bounds__(256) void k_ktv(const u16* __restrict__ kb,
                                             const u16* __restrict__ vWb,
                                             float* __restrict__ part, int M)
{
    __shared__ u16 kT[D * 64];
    __shared__ u16 vT[D * 64];
    const int t = threadIdx.x;
    const int P = (int)gridDim.x;
    const int chunk = (M + P - 1) / P;
    const int rbeg = blockIdx.x * chunk;
    const int rend = min(rbeg + chunk, M);

    const int lane = t & 63, w = t >> 6;
    const int fr = lane & 15, kg = lane >> 4;

    f32x4 acc[2][8] = {};

    for (int r0 = rbeg; r0 < rend; r0 += 64) {
#pragma unroll
        for (int p = 0; p < 4; ++p) {
            const int flat = t + 256 * p;
            const int rr = flat & 63, cg = flat >> 6;
            const int gr = r0 + rr;
            uint4 kv = make_uint4(0, 0, 0, 0), vv = make_uint4(0, 0, 0, 0);
            if (gr < rend) {
                kv = *(const uint4*)(kb + (size_t)gr * D + cg * 8);
                vv = *(const uint4*)(vWb + (size_t)gr * D + cg * 8);
            }
            const u16* kp = (const u16*)&kv;
            const u16* vp = (const u16*)&vv;
#pragma unroll
            for (int jj = 0; jj < 8; ++jj) {
                const int c = cg * 8 + jj;
                const int ri = rr ^ ((c & 7) << 3);
                kT[c * 64 + ri] = kp[jj];
                vT[c * 64 + ri] = vp[jj];
            }
        }
        __syncthreads();
#pragma unroll
        for (int ks = 0; ks < 2; ++ks) {
            const int rb = ks * 32 + kg * 8;
            bf16x8 a[2], b[8];
#pragma unroll
            for (int i = 0; i < 2; ++i) {
                const int m = w * 32 + 16 * i + fr;
                a[i] = *(const bf16x8*)(kT + m * 64 + (rb ^ ((m & 7) << 3)));
            }
#pragma unroll
            for (int j = 0; j < 8; ++j) {
                const int n = 16 * j + fr;
                b[j] = *(const bf16x8*)(vT + n * 64 + (rb ^ ((n & 7) << 3)));
            }
#pragma unroll
            for (int i = 0; i < 2; ++i)
#pragma unroll
                for (int j = 0; j < 8; ++j)
                    acc[i][j] = __builtin_amdgcn_mfma_f32_16x16x32_bf16(a[i], b[j], acc[i][j], 0, 0, 0);
        }
        __syncthreads();
    }
    float* pp = part + (size_t)blockIdx.x * (D * D);
#pragma unroll
    for (int i = 0; i < 2; ++i)
#pragma unroll
        for (int reg = 0; reg < 4; ++reg) {
            const int m = w * 32 + 16 * i + kg * 4 + reg;
#pragma unroll
            for (int j = 0; j < 8; ++j)
                pp[(size_t)m * D + 16 * j + fr] = acc[i][j][reg];
        }
}

// unrolled split-K reduce: 8 independent loads in flight per thread
__global__ void k_redC(const float* __restrict__ part, float* __restrict__ Craw, int P)
{
    const int e = blockIdx.x * 256 + threadIdx.x; // 16384
    float s0 = 0.f, s1 = 0.f, s2 = 0.f, s3 = 0.f,
          s4 = 0.f, s5 = 0.f, s6 = 0.f, s7 = 0.f;
    int p = 0;
    for (; p + 8 <= P; p += 8) {
        s0 += part[(size_t)(p + 0) * (D * D) + e];
        s1 += part[(size_t)(p + 1) * (D * D) + e];
        s2 += part[(size_t)(p + 2) * (D * D) + e];
        s3 += part[(size_t)(p + 3) * (D * D) + e];
        s4 += part[(size_t)(p + 4) * (D * D) + e];
        s5 += part[(size_t)(p + 5) * (D * D) + e];
        s6 += part[(size_t)(p + 6) * (D * D) + e];
        s7 += part[(size_t)(p + 7) * (D * D) + e];
    }
    for (; p < P; ++p) s0 += part[(size_t)p * (D * D) + e];
    Craw[e] = ((s0 + s1) + (s2 + s3)) + ((s4 + s5) + (s6 + s7));
}

// ---------------- merged: reduce stats partials -> kq, inv; emit C3b ----------------
// 1 block x 1024 threads; NBLK arbitrary (loops handle > 1024).
__global__ __launch_bounds__(1024) void k_scalc3t(const float* __restrict__ psq,
                                                  const float* __restrict__ psk,
                                                  const float* __restrict__ pks,
                                                  const float* __restrict__ Craw,
                                                  float* __restrict__ kq,
                                                  u16* __restrict__ C3b, int NBLK)
{
    __shared__ float lpart[8][D];
    __shared__ float wredA[16];
    __shared__ float wredB[16];
    __shared__ float invS;
    const int t = threadIdx.x;
    const int col = t & 127, grp = t >> 7; // 8 groups x 128 cols
    float s = 0.f;
#pragma unroll 8
    for (int bq = grp; bq < NBLK; bq += 8) s += pks[(size_t)bq * D + col];
    lpart[grp][col] = s;
    // sumsq reduce (any NBLK)
    const int w = t >> 6, lane = t & 63;
    float a = 0.f, b = 0.f;
    for (int i = t; i < NBLK; i += 1024) { a += psq[i]; b += psk[i]; }
    for (int off = 32; off > 0; off >>= 1) {
        a += __shfl_down(a, off);
        b += __shfl_down(b, off);
    }
    if (lane == 0) { wredA[w] = a; wredB[w] = b; }
    __syncthreads();
    if (t == 0) {
        float sq = 0.f, sk = 0.f;
#pragma unroll
        for (int i = 0; i < 16; ++i) { sq += wredA[i]; sk += wredB[i]; }
        invS = 1.0f / (sqrtf(sq) * sqrtf(sk) * 128.0f);
    }
    float ks = 0.f;
    if (t < D) {
#pragma unroll
        for (int g = 0; g < 8; ++g) ks += lpart[g][t];
    }
    __syncthreads();
    const float inv = invS;
    if (t < D) kq[t] = ks * inv;
#pragma unroll
    for (int i = 0; i < 16; ++i) {
        const int e = t + 1024 * i;
        C3b[e] = f2b(Craw[(size_t)(e & 127) * D + (e >> 7)] * inv);
    }
}

// ---------------- K4: MFMA qb @ C3b^T + fused qk/scale + epilogue ----------------
__global__ __launch_bounds__(256) void k_final(const u16* __restrict__ qb,
                                               const u16* __restrict__ C3b,
                                               const u16* __restrict__ vWb,
                                               const u16* __restrict__ xWb,
                                               const u16* __restrict__ ub,
                                               const int* __restrict__ cnt,
                                               const float* __restrict__ kq,
                                               const float* __restrict__ biasout,
                                               float* __restrict__ out, int M)
{
    __shared__ u16 As[64 * D];
    __shared__ u16 Bs[D * D];
    __shared__ float scaleS[64];
    const int t = threadIdx.x;
    const int row0 = blockIdx.x * 64;

#pragma unroll
    for (int p = 0; p < 4; ++p) {
        const int flat = t + 256 * p;
        const int r = flat >> 4, kg2 = flat & 15;
        int gr = row0 + r; if (gr > M - 1) gr = M - 1;
        const uint4 v = *(const uint4*)(qb + (size_t)gr * D + kg2 * 8);
        *(uint4*)(As + r * D + SWZ(r, kg2 * 8)) = v;
    }
#pragma unroll
    for (int p = 0; p < 8; ++p) {
        const int flat = t + 256 * p;
        const int r = flat >> 4, kg2 = flat & 15;
        const uint4 v = *(const uint4*)(C3b + (size_t)r * D + kg2 * 8);
        *(uint4*)(Bs + r * D + SWZ(r, kg2 * 8)) = v;
    }
    __syncthreads();

    {
        const int rr = t >> 2, qq = t & 3;
        float s = 0.f;
#pragma unroll
        for (int i = 0; i < 4; ++i) {
            const int kk = qq * 32 + i * 8;
            const bf16x8 a = *(const bf16x8*)(As + rr * D + SWZ(rr, kk));
            const u16* ap = (const u16*)&a;
#pragma unroll
            for (int jj = 0; jj < 8; ++jj) s += b2f(ap[jj]) * kq[kk + jj];
        }
        s += __shfl_xor(s, 1);
        s += __shfl_xor(s, 2);
        if (qq == 0) scaleS[rr] = 0.16f / (1.0f + s);
    }

    const int lane = t & 63, w = t >> 6;
    const int fr = lane & 15, kg = lane >> 4;

    f32x4 acc[8] = {};
#pragma unroll
    for (int ks = 0; ks < 4; ++ks) {
        const int kb2 = ks * 32 + kg * 8;
        const int r = w * 16 + fr;
        const bf16x8 a = *(const bf16x8*)(As + r * D + SWZ(r, kb2));
#pragma unroll
        for (int j = 0; j < 8; ++j) {
            const int n = 16 * j + fr;
            const bf16x8 b = *(const bf16x8*)(Bs + n * D + SWZ(n, kb2));
            acc[j] = __builtin_amdgcn_mfma_f32_16x16x32_bf16(a, b, acc[j], 0, 0, 0);
        }
    }
    __syncthreads(); // scaleS ready

#pragma unroll
    for (int reg = 0; reg < 4; ++reg) {
        const int rr = w * 16 + kg * 4 + reg;
        const int r = row0 + rr;
        if (r < M) {
            const float rc = scaleS[rr];
            const float sc = 1.0f / (float)(cnt[r] + 1);
#pragma unroll
            for (int j = 0; j < 8; ++j) {
                const int c = 16 * j + fr;
                const size_t idx = (size_t)r * D + c;
                out[idx] = rc * (b2f(vWb[idx]) + acc[j][reg]) + 0.24f * b2f(xWb[idx])
                         + biasout[c] + sc * b2f(ub[idx]);
            }
        }
    }
}

// ---------------- K5: wave-cooperative CSR gather (packed payload) ----------------
__global__ __launch_bounds__(256) void k_gather(const int* __restrict__ offs,
                                                const int* __restrict__ cnt,
                                                const uint32_t* __restrict__ cpk,
                                                const u16* __restrict__ ub,
                                                float* __restrict__ out, int M)
{
    const int t = threadIdx.x;
    const int w = t >> 6, lane = t & 63;
    const int d = blockIdx.x * 4 + w;
    if (d >= M) return;
    const int g = lane >> 4, sub = lane & 15;
    const int beg = offs[d];
    const int n = cnt[d];
    if (n == 0) return;
    const int end = beg + n;
    float acc[8] = {};
    for (int j0 = beg; j0 < end; j0 += 8) {
        const int j1 = j0 + g, j2 = j0 + 4 + g;
        int s1 = 0, s2 = 0;
        float w1 = 0.f, w2 = 0.f;
        if (j1 < end) {
            const uint32_t p = cpk[j1];
            s1 = (int)(p & 0xFFFFu);
            w1 = __half2float(__ushort_as_half((u16)(p >> 16)));
        }
        if (j2 < end) {
            const uint32_t p = cpk[j2];
            s2 = (int)(p & 0xFFFFu);
            w2 = __half2float(__ushort_as_half((u16)(p >> 16)));
        }
        const uint4 r1 = *(const uint4*)(ub + (size_t)s1 * D + sub * 8);
        const uint4 r2 = *(const uint4*)(ub + (size_t)s2 * D + sub * 8);
        const u16* p1 = (const u16*)&r1;
        const u16* p2 = (const u16*)&r2;
#pragma unroll
        for (int i = 0; i < 8; ++i) acc[i] += w1 * b2f(p1[i]) + w2 * b2f(p2[i]);
    }
#pragma unroll
    for (int i = 0; i < 8; ++i) {
        acc[i] += __shfl_xor(acc[i], 16);
        acc[i] += __shfl_xor(acc[i], 32);
    }
    if (g == 0) {
        float* o = out + (size_t)d * D + sub * 8;
        float4 o0 = *(float4*)o, o1 = *(float4*)(o + 4);
        o0.x += acc[0]; o0.y += acc[1]; o0.z += acc[2]; o0.w += acc[3];
        o1.x += acc[4]; o1.y += acc[5]; o1.z += acc[6]; o1.w += acc[7];
        *(float4*)o = o0; *(float4*)(o + 4) = o1;
    }
}

extern "C" void kernel_launch(void* const* d_in, const int* in_sizes, int n_in,
                              void* d_out, int out_size, void* d_ws, size_t ws_size,
                              hipStream_t stream)
{
    const float* x  = (const float*)d_in[0];
    const int*   ei = (const int*)d_in[1];
    const float* Wq = (const float*)d_in[2];
    const float* Wk = (const float*)d_in[3];
    const float* Wv = (const float*)d_in[4];
    const float* Wg = (const float*)d_in[5];
    const float* bg = (const float*)d_in[6];
    const float* Wl = (const float*)d_in[7];
    const float* bl = (const float*)d_in[8];

    const int M = in_sizes[0] / D;
    const int E = in_sizes[1] / 2;
    const size_t NQ = (size_t)M * D;
    const int P = 192;
    const int NBG = (M + 63) / 64;      // row strips = stats partials
    const int NB = (M + 1023) / 1024;

    char* base = (char*)d_ws;
    auto alloc = [&](size_t bytes) -> char* {
        char* p = base; base += (bytes + 63) & ~(size_t)63; return p;
    };
    float* part    = (float*)alloc((size_t)P * D * D * 4);
    float* Craw    = (float*)alloc(D * D * 4);
    float* dinv    = (float*)alloc((size_t)M * 4);
    float* psq     = (float*)alloc((size_t)NBG * 4);
    float* psk     = (float*)alloc((size_t)NBG * 4);
    float* pks     = (float*)alloc((size_t)NBG * D * 4);
    float* kq      = (float*)alloc(D * 4);
    float* biasout = (float*)alloc(D * 4);
    int*   cnt     = (int*)alloc((size_t)M * 4);
    int*   offs    = (int*)alloc((size_t)M * 4);
    int*   bsum    = (int*)alloc(64 * 4);
    int*   epos    = (int*)alloc((size_t)E * 4);
    uint32_t* cpk  = (uint32_t*)alloc((size_t)E * 4);
    u16*   Bcatb   = (u16*)alloc((size_t)640 * D * 2);
    u16*   C3b     = (u16*)alloc(D * D * 2);
    u16*   qb      = (u16*)alloc(NQ * 2); // qb..ub contiguous
    u16*   kb      = (u16*)alloc(NQ * 2);
    u16*   vWb     = (u16*)alloc(NQ * 2);
    u16*   xWb     = (u16*)alloc(NQ * 2);
    u16*   ub      = (u16*)alloc(NQ * 2);
    (void)kb; (void)vWb; (void)xWb;

    float* out = (float*)d_out;

    // weights + CSR build
    k_prep<<<dim3(641), dim3(128), 0, stream>>>(Wq, Wk, Wv, Wg, bg, Wl, bl, Bcatb, biasout);
    k_init<<<(M + 255) / 256, 256, 0, stream>>>(cnt, M);
    k_hist<<<(E + 255) / 256, 256, 0, stream>>>(ei + E, cnt, epos, E);
    k_scan1<<<NB, 1024, 0, stream>>>(cnt, offs, bsum, dinv, M);
    k_scanB<<<1, 64, 0, stream>>>(bsum, NB);
    k_scan2<<<(M + 255) / 256, 256, 0, stream>>>(bsum, offs, M);
    k_fill<<<(E + 255) / 256, 256, 0, stream>>>(ei, ei + E, epos, dinv, offs, cpk, E);

    // dense chain (bf16 MFMA)
    k_gemm5<<<dim3(NBG, 5), 256, 0, stream>>>(x, Bcatb, qb, psq, psk, pks, M, NQ);
    k_ktv<<<P, 256, 0, stream>>>(kb, vWb, part, M);
    k_redC<<<64, 256, 0, stream>>>(part, Craw, P);
    k_scalc3t<<<1, 1024, 0, stream>>>(psq, psk, pks, Craw, kq, C3b, NBG);

    k_final<<<(M + 63) / 64, 256, 0, stream>>>(qb, C3b, vWb, xWb, ub, cnt, kq, biasout, out, M);
    k_gather<<<(M + 3) / 4, 256, 0, stream>>>(offs, cnt, cpk, ub, out, M);
}